// Round 11
// baseline (509.305 us; speedup 1.0000x reference)
//
#include <hip/hip_runtime.h>
#include <hip/hip_bf16.h>

#define N 8192
#define HID 64
#define JC 16   // J-chunks per I-tile: grid = 128*JC = 2048 blocks

typedef __attribute__((ext_vector_type(4))) float f32x4;
typedef __attribute__((ext_vector_type(8))) __bf16 bf16x8;

// ---------------- Kernel M: pos (f32, binary) -> nibble byte-mask ----------
// 268MB -> 16MB, fully-coalesced streaming (1KB/wave-inst reads).
// byte[i] bit r = (pos[4i+r] != 0). Rebuilt every iteration (ws is poisoned).
__global__ __launch_bounds__(256) void mask_kernel(
    const float* __restrict__ pos, unsigned char* __restrict__ mask)
{
  int idx = blockIdx.x * 256 + threadIdx.x;        // grid 2048 -> 0..524287
  const int stride = 2048 * 256;
  #pragma unroll 1
  for (int it = 0; it < 32; ++it) {                // 16,777,216 bytes total
    int i = idx + it * stride;
    f32x4 v = *(const f32x4*)(pos + (size_t)i * 4);
    unsigned b = (unsigned)(v.x != 0.f) | ((unsigned)(v.y != 0.f) << 1)
               | ((unsigned)(v.z != 0.f) << 2) | ((unsigned)(v.w != 0.f) << 3);
    mask[i] = (unsigned char)b;
  }
}

// ---------------- Kernel A: projection + L2 normalize -> bf16 ----------------
// h = elu(x @ W1^T + b1); z = h @ W2^T + b2; zhat = z / max(||z||, 1e-12)
// One wave per row-iteration; lane j = output feature j. W1/W2 in LDS with
// stride-68 padding. Also zero-inits the 4*N stat array (replaces memset).
__global__ __launch_bounds__(256) void proj_kernel(
    const float* __restrict__ x1, const float* __restrict__ x2,
    const float* __restrict__ W1, const float* __restrict__ b1,
    const float* __restrict__ W2, const float* __restrict__ b2,
    __bf16* __restrict__ Z1h, __bf16* __restrict__ Z2h,
    float* __restrict__ stats)
{
  __shared__ __align__(16) float w1s[64*68];
  __shared__ __align__(16) float w2s[64*68];
  __shared__ __align__(16) float xs[4][64];
  __shared__ __align__(16) float hs[4][64];

  const int tid  = threadIdx.x;
  const int lane = tid & 63;
  const int w    = tid >> 6;

  int gtid = blockIdx.x * 256 + tid;
  if (gtid < 4*N) stats[gtid] = 0.f;

  for (int idx = tid; idx < 64*64; idx += 256) {
    int j = idx >> 6, k = idx & 63;
    w1s[j*68+k] = W1[idx];
    w2s[j*68+k] = W2[idx];
  }
  __syncthreads();

  const float bias1 = b1[lane];
  const float bias2 = b2[lane];

  const int wave_global = blockIdx.x * 4 + w;   // 0..4095 with grid=1024
  #pragma unroll 1
  for (int it = 0; it < 4; ++it) {
    int R = wave_global * 4 + it;               // 0..16383
    const float* src; __bf16* dst;
    if (R < N) { src = x1 + (size_t)R*HID;      dst = Z1h + (size_t)R*HID; }
    else       { src = x2 + (size_t)(R-N)*HID;  dst = Z2h + (size_t)(R-N)*HID; }

    float xv = src[lane];
    xs[w][lane] = xv;
    float acc = bias1;
    #pragma unroll
    for (int qq = 0; qq < 16; ++qq) {
      f32x4 xq = *(const f32x4*)&xs[w][qq*4];
      f32x4 wq = *(const f32x4*)&w1s[lane*68 + qq*4];
      acc += xq.x*wq.x + xq.y*wq.y + xq.z*wq.z + xq.w*wq.w;
    }
    float h = acc > 0.f ? acc : expm1f(acc);             // ELU (alpha=1)
    hs[w][lane] = h;
    float acc2 = bias2;
    #pragma unroll
    for (int qq = 0; qq < 16; ++qq) {
      f32x4 hq = *(const f32x4*)&hs[w][qq*4];
      f32x4 wq = *(const f32x4*)&w2s[lane*68 + qq*4];
      acc2 += hq.x*wq.x + hq.y*wq.y + hq.z*wq.z + hq.w*wq.w;
    }
    float z = acc2;
    float ss = z*z;
    #pragma unroll
    for (int m = 1; m < 64; m <<= 1) ss += __shfl_xor(ss, m);
    float inv = 1.0f / fmaxf(sqrtf(ss), 1e-12f);
    dst[lane] = (__bf16)(z * inv);
  }
}

// ---------------- Kernel B: exp-sim, barrier-free TLP + byte-mask ----------
// The R0 structure (direct L2-resident Z-frag loads, NO LDS, NO barriers, no
// inline asm) with R10's byte-mask replacing the scattered pos floats.
// Causal story: R0's 165us was pos-scattered-HBM (~134us); R10 showed the
// barrier/stage skeleton itself costs ~110us even with pos free (m233's
// 2-phase overhead). So: remove BOTH. Main loop = 8 Z loads + 8 MFMA +
// 16 exp + gated adds per 32-col step; ~250cy L2 latency hidden by 6+
// waves/SIMD of independent streams (m114 TLP). All 8 mask words for the
// 512-col sweep are preloaded per wave (8 u32, static names) -> zero in-loop
// mask traffic. Swapped-operand MFMA (verified absmax 0): lane (q,r16),
// reg r = element (i = i0+r16, j = J0 + q*4 + r); mask bit (8q+r) of the
// k-th subtile word (shfl from lane k*16+r16) gates n += e (bit-exact vs
// e*pv, pv in {0,1}).
__global__ __launch_bounds__(256) void sim_kernel(
    const __bf16* __restrict__ Z1h, const __bf16* __restrict__ Z2h,
    const unsigned char* __restrict__ mask,
    float* __restrict__ rowsum1, float* __restrict__ num1,
    float* __restrict__ rowsum2, float* __restrict__ num2)
{
  const int tid  = threadIdx.x;
  const int lane = tid & 63;
  const int w    = tid >> 6;
  const int r16  = lane & 15;
  const int q    = lane >> 4;

  const int bi = blockIdx.x / JC;   // 0..127 I-tile
  const int jc = blockIdx.x % JC;
  const int i0 = bi*64 + w*16;

  // i-side fragments (B-operand after swap): row i0+r16, k = q*8 (lo) / +32 (hi)
  const __bf16* z1r = Z1h + (size_t)(i0 + r16)*HID + q*8;
  const __bf16* z2r = Z2h + (size_t)(i0 + r16)*HID + q*8;
  const bf16x8 a1lo = *(const bf16x8*)(z1r);
  const bf16x8 a1hi = *(const bf16x8*)(z1r + 32);
  const bf16x8 a2lo = *(const bf16x8*)(z2r);
  const bf16x8 a2hi = *(const bf16x8*)(z2r + 32);

  const int jbeg = jc * (N/JC);               // 512-col sweep, 8 x 64-col groups
  const float Cexp = 1.8033688011112042f;     // 1/(TAU*ln2), TAU=0.8

  // all 8 mask words for this wave's sweep: row i0+r16, 64 cols per word
  // word g = u32 at mask[(i0+r16)*(N/4) + jbeg/4 + g*16 + q*4]   (R10 layout)
  const unsigned char* mrow = mask + (size_t)(i0 + r16)*(N/4) + (jbeg >> 2) + q*4;
  const unsigned MK0 = *(const unsigned*)(mrow + 0*16);
  const unsigned MK1 = *(const unsigned*)(mrow + 1*16);
  const unsigned MK2 = *(const unsigned*)(mrow + 2*16);
  const unsigned MK3 = *(const unsigned*)(mrow + 3*16);
  const unsigned MK4 = *(const unsigned*)(mrow + 4*16);
  const unsigned MK5 = *(const unsigned*)(mrow + 5*16);
  const unsigned MK6 = *(const unsigned*)(mrow + 6*16);
  const unsigned MK7 = *(const unsigned*)(mrow + 7*16);

  float s1 = 0.f, n1 = 0.f, s2 = 0.f, n2 = 0.f;

  // one 16-col j-subtile at col J0: direct L2 loads + MFMA pair + exp + acc
#define COMPC(J0, MK) { \
    const __bf16* zj2 = Z2h + (size_t)((J0) + r16)*HID + q*8; \
    const __bf16* zj1 = Z1h + (size_t)((J0) + r16)*HID + q*8; \
    bf16x8 b2lo = *(const bf16x8*)(zj2); \
    bf16x8 b2hi = *(const bf16x8*)(zj2 + 32); \
    bf16x8 b1lo = *(const bf16x8*)(zj1); \
    bf16x8 b1hi = *(const bf16x8*)(zj1 + 32); \
    f32x4 zero4 = {0.f,0.f,0.f,0.f}; \
    f32x4 d1 = __builtin_amdgcn_mfma_f32_16x16x32_bf16(b2lo, a1lo, zero4, 0,0,0); \
    d1       = __builtin_amdgcn_mfma_f32_16x16x32_bf16(b2hi, a1hi, d1,    0,0,0); \
    f32x4 d2 = __builtin_amdgcn_mfma_f32_16x16x32_bf16(b1lo, a2lo, zero4, 0,0,0); \
    d2       = __builtin_amdgcn_mfma_f32_16x16x32_bf16(b1hi, a2hi, d2,    0,0,0); \
    _Pragma("unroll") \
    for (int r = 0; r < 4; ++r) { \
      float e1 = exp2f(d1[r] * Cexp); \
      float e2 = exp2f(d2[r] * Cexp); \
      s1 += e1; s2 += e2; \
      if (((MK) >> (8*q + r)) & 1u) { n1 += e1; n2 += e2; } \
    } }

  // one 64-col group: route subtile words (k=0..3 from lane k*16+r16), 4 subtiles
#define GROUP(G, MKG) { \
    const int j0 = jbeg + (G)*64; \
    const unsigned Mk0 = __shfl((int)(MKG),      r16); \
    const unsigned Mk1 = __shfl((int)(MKG), 16 + r16); \
    const unsigned Mk2 = __shfl((int)(MKG), 32 + r16); \
    const unsigned Mk3 = __shfl((int)(MKG), 48 + r16); \
    COMPC(j0,      Mk0) \
    COMPC(j0 + 16, Mk1) \
    COMPC(j0 + 32, Mk2) \
    COMPC(j0 + 48, Mk3) }

  GROUP(0, MK0)
  GROUP(1, MK1)
  GROUP(2, MK2)
  GROUP(3, MK3)
  GROUP(4, MK4)
  GROUP(5, MK5)
  GROUP(6, MK6)
  GROUP(7, MK7)

#undef COMPC
#undef GROUP

  // reduce j-partials across the 4 quads -> full sums per row i0+r16
  s1 += __shfl_xor(s1, 16); s1 += __shfl_xor(s1, 32);
  n1 += __shfl_xor(n1, 16); n1 += __shfl_xor(n1, 32);
  s2 += __shfl_xor(s2, 16); s2 += __shfl_xor(s2, 32);
  n2 += __shfl_xor(n2, 16); n2 += __shfl_xor(n2, 32);

  if (lane < 16) {
    int row = i0 + r16;
    atomicAdd(&rowsum1[row], s1);
    atomicAdd(&num1[row],    n1);
    atomicAdd(&rowsum2[row], s2);
    atomicAdd(&num2[row],    n2);
  }
}

// ---------------- Kernel C: final loss reduction ----------------
__global__ __launch_bounds__(1024) void loss_kernel(
    const float* __restrict__ rowsum1, const float* __restrict__ num1,
    const float* __restrict__ rowsum2, const float* __restrict__ num2,
    float* __restrict__ out)
{
  __shared__ float part[16];
  const int tid = threadIdx.x, lane = tid & 63, w = tid >> 6;
  float acc = 0.f;
  for (int i = tid; i < N; i += 1024) {
    float sc = -logf(num1[i]/(rowsum1[i]+1e-8f) + 1e-8f);
    float mp = -logf(num2[i]/(rowsum2[i]+1e-8f) + 1e-8f);
    acc += 0.5f*sc + 0.5f*mp;   // LAMBDA = 0.5
  }
  #pragma unroll
  for (int m = 1; m < 64; m <<= 1) acc += __shfl_xor(acc, m);
  if (lane == 0) part[w] = acc;
  __syncthreads();
  if (tid == 0) {
    float t = 0.f;
    #pragma unroll
    for (int k = 0; k < 16; ++k) t += part[k];
    out[0] = t * (1.0f/N);
  }
}

extern "C" void kernel_launch(void* const* d_in, const int* in_sizes, int n_in,
                              void* d_out, int out_size, void* d_ws, size_t ws_size,
                              hipStream_t stream) {
  const float* x1  = (const float*)d_in[0];
  const float* x2  = (const float*)d_in[1];
  const float* W1  = (const float*)d_in[2];
  const float* b1  = (const float*)d_in[3];
  const float* W2  = (const float*)d_in[4];
  const float* b2  = (const float*)d_in[5];
  const float* pos = (const float*)d_in[6];

  char* ws = (char*)d_ws;
  __bf16* Z1h = (__bf16*)ws;
  __bf16* Z2h = (__bf16*)(ws + (size_t)N*HID*sizeof(__bf16));
  size_t zbytes = (size_t)2*N*HID*sizeof(__bf16);   // 2 MB
  float* rowsum1 = (float*)(ws + zbytes);
  float* num1    = rowsum1 + N;
  float* rowsum2 = num1 + N;
  float* num2    = rowsum2 + N;
  unsigned char* mask = (unsigned char*)(ws + zbytes + (size_t)4*N*sizeof(float)); // 16 MB

  mask_kernel<<<2048, 256, 0, stream>>>(pos, mask);
  proj_kernel<<<1024, 256, 0, stream>>>(x1, x2, W1, b1, W2, b2, Z1h, Z2h, rowsum1);
  sim_kernel<<<128*JC, 256, 0, stream>>>(Z1h, Z2h, mask, rowsum1, num1, rowsum2, num2);
  loss_kernel<<<1, 1024, 0, stream>>>(rowsum1, num1, rowsum2, num2, (float*)d_out);
}

// Round 13
// 415.814 us; speedup vs baseline: 1.2248x; 1.2248x over previous
//
#include <hip/hip_runtime.h>
#include <hip/hip_bf16.h>

#define N 8192
#define HID 64
#define JC 8    // J-chunks per I-tile: grid = 128*JC = 1024 blocks, 4/CU resident

typedef __attribute__((ext_vector_type(4))) float f32x4;
typedef __attribute__((ext_vector_type(8))) __bf16 bf16x8;

// raw v_exp_f32 (2^x): our args are |x| <= ~2.3, so the bare instruction is
// exact — avoids the OCML exp2f slow path (range checks + fixups, ~6-10 VALU
// ops per call x 134M calls).
#if __has_builtin(__builtin_amdgcn_exp2f)
__device__ __forceinline__ float fast_exp2(float x) {
  return __builtin_amdgcn_exp2f(x);
}
#else
__device__ __forceinline__ float fast_exp2(float x) {
  float r;
  asm volatile("v_exp_f32 %0, %1" : "=v"(r) : "v"(x));
  return r;
}
#endif

// async global->LDS, 16B per lane, dest = wave-uniform base + lane*16
__device__ __forceinline__ void gload_lds16(const void* g, float* l) {
  __builtin_amdgcn_global_load_lds(
      (const __attribute__((address_space(1))) void*)g,
      (__attribute__((address_space(3))) void*)l, 16, 0, 0);
}

// ---------------- Kernel A: projection + L2 normalize -> bf16 ----------------
// h = elu(x @ W1^T + b1); z = h @ W2^T + b2; zhat = z / max(||z||, 1e-12)
// One wave per row-iteration; lane j = output feature j. W1/W2 in LDS with
// stride-68 padding. Also zero-inits the 4*N stat array (replaces memset).
__global__ __launch_bounds__(256) void proj_kernel(
    const float* __restrict__ x1, const float* __restrict__ x2,
    const float* __restrict__ W1, const float* __restrict__ b1,
    const float* __restrict__ W2, const float* __restrict__ b2,
    __bf16* __restrict__ Z1h, __bf16* __restrict__ Z2h,
    float* __restrict__ stats)
{
  __shared__ __align__(16) float w1s[64*68];
  __shared__ __align__(16) float w2s[64*68];
  __shared__ __align__(16) float xs[4][64];
  __shared__ __align__(16) float hs[4][64];

  const int tid  = threadIdx.x;
  const int lane = tid & 63;
  const int w    = tid >> 6;

  int gtid = blockIdx.x * 256 + tid;
  if (gtid < 4*N) stats[gtid] = 0.f;

  for (int idx = tid; idx < 64*64; idx += 256) {
    int j = idx >> 6, k = idx & 63;
    w1s[j*68+k] = W1[idx];
    w2s[j*68+k] = W2[idx];
  }
  __syncthreads();

  const float bias1 = b1[lane];
  const float bias2 = b2[lane];

  const int wave_global = blockIdx.x * 4 + w;   // 0..4095 with grid=1024
  #pragma unroll 1
  for (int it = 0; it < 4; ++it) {
    int R = wave_global * 4 + it;               // 0..16383
    const float* src; __bf16* dst;
    if (R < N) { src = x1 + (size_t)R*HID;      dst = Z1h + (size_t)R*HID; }
    else       { src = x2 + (size_t)(R-N)*HID;  dst = Z2h + (size_t)(R-N)*HID; }

    float xv = src[lane];
    xs[w][lane] = xv;
    float acc = bias1;
    #pragma unroll
    for (int qq = 0; qq < 16; ++qq) {
      f32x4 xq = *(const f32x4*)&xs[w][qq*4];
      f32x4 wq = *(const f32x4*)&w1s[lane*68 + qq*4];
      acc += xq.x*wq.x + xq.y*wq.y + xq.z*wq.z + xq.w*wq.w;
    }
    float h = acc > 0.f ? acc : expm1f(acc);             // ELU (alpha=1)
    hs[w][lane] = h;
    float acc2 = bias2;
    #pragma unroll
    for (int qq = 0; qq < 16; ++qq) {
      f32x4 hq = *(const f32x4*)&hs[w][qq*4];
      f32x4 wq = *(const f32x4*)&w2s[lane*68 + qq*4];
      acc2 += hq.x*wq.x + hq.y*wq.y + hq.z*wq.z + hq.w*wq.w;
    }
    float z = acc2;
    float ss = z*z;
    #pragma unroll
    for (int m = 1; m < 64; m <<= 1) ss += __shfl_xor(ss, m);
    float inv = 1.0f / fmaxf(sqrtf(ss), 1e-12f);
    dst[lane] = (__bf16)(z * inv);
  }
}

// ---------------- Kernel B: exp-sim (R8 skeleton + raw v_exp_f32) ----------
// Verbatim the verified R8 structure (best passing: total 419us, absmax 0):
// 2-phase global_load_lds double-buffer for Z (swizzled source, linear dest),
// pos f32x4 register banks issued one phase ahead, __syncthreads sync.
// ONLY change this round: exp2f -> fast_exp2 (bare v_exp_f32).
__global__ __launch_bounds__(256, 4) void sim_kernel(
    const __bf16* __restrict__ Z1h, const __bf16* __restrict__ Z2h,
    const float* __restrict__ pos,
    float* __restrict__ rowsum1, float* __restrict__ num1,
    float* __restrict__ rowsum2, float* __restrict__ num2)
{
  __shared__ __align__(16) float zs1[2][2048];   // 64 rows x 128B, double buf
  __shared__ __align__(16) float zs2[2][2048];   // 32 KB total

  const int tid  = threadIdx.x;
  const int lane = tid & 63;
  const int w    = tid >> 6;
  const int r16  = lane & 15;
  const int q    = lane >> 4;

  const int bi  = blockIdx.x / JC;    // 0..127 I-tile
  const int jc  = blockIdx.x % JC;
  const int i0  = bi*64 + w*16;

  // i-side fragments: row i0+r16, k = q*8 (lo) / +32 (hi)
  const __bf16* z1r = Z1h + (size_t)(i0 + r16)*HID + q*8;
  const __bf16* z2r = Z2h + (size_t)(i0 + r16)*HID + q*8;
  const bf16x8 a1lo = *(const bf16x8*)(z1r);
  const bf16x8 a1hi = *(const bf16x8*)(z1r + 32);
  const bf16x8 a2lo = *(const bf16x8*)(z2r);
  const bf16x8 a2hi = *(const bf16x8*)(z2r + 32);

  float s1 = 0.f, n1 = 0.f, s2 = 0.f, n2 = 0.f;

  const int jbeg = jc * (N/JC);               // 1024-col chunk, 16 x 64-col steps
  const float Cexp = 1.8033688011112042f;     // 1/(TAU*ln2), TAU=0.8
  const float* prow = pos + (size_t)(i0 + r16)*N + q*4;

  f32x4 PA0, PA1, PA2, PA3, PB0, PB1, PB2, PB3;   // pos banks, static names

#define STAGEZ(BUF, JJ) { \
    const int r8 = lane >> 3; \
    const int sl = (lane & 7) ^ r8; \
    gload_lds16(Z1h + (size_t)((JJ) + w*16     + r8)*HID + sl*8, &zs1[BUF][(w*16    )*32]); \
    gload_lds16(Z1h + (size_t)((JJ) + w*16 + 8 + r8)*HID + sl*8, &zs1[BUF][(w*16 + 8)*32]); \
    gload_lds16(Z2h + (size_t)((JJ) + w*16     + r8)*HID + sl*8, &zs2[BUF][(w*16    )*32]); \
    gload_lds16(Z2h + (size_t)((JJ) + w*16 + 8 + r8)*HID + sl*8, &zs2[BUF][(w*16 + 8)*32]); \
  }

#define LOADPOS(P, JJ) { \
    P##0 = *(const f32x4*)(prow + (JJ)); \
    P##1 = *(const f32x4*)(prow + (JJ) + 16); \
    P##2 = *(const f32x4*)(prow + (JJ) + 32); \
    P##3 = *(const f32x4*)(prow + (JJ) + 48); \
  }

#define COMPC(BUF, C, CC, PV) { \
    const int R  = (CC) + (C)*16 + r16; \
    const int sw = r16 & 7; \
    bf16x8 b2lo = *(const bf16x8*)&zs2[BUF][R*32 + ((q    ) ^ sw)*4]; \
    bf16x8 b2hi = *(const bf16x8*)&zs2[BUF][R*32 + ((q + 4) ^ sw)*4]; \
    bf16x8 b1lo = *(const bf16x8*)&zs1[BUF][R*32 + ((q    ) ^ sw)*4]; \
    bf16x8 b1hi = *(const bf16x8*)&zs1[BUF][R*32 + ((q + 4) ^ sw)*4]; \
    f32x4 zero4 = {0.f,0.f,0.f,0.f}; \
    f32x4 d1 = __builtin_amdgcn_mfma_f32_16x16x32_bf16(b2lo, a1lo, zero4, 0,0,0); \
    d1       = __builtin_amdgcn_mfma_f32_16x16x32_bf16(b2hi, a1hi, d1,    0,0,0); \
    f32x4 d2 = __builtin_amdgcn_mfma_f32_16x16x32_bf16(b1lo, a2lo, zero4, 0,0,0); \
    d2       = __builtin_amdgcn_mfma_f32_16x16x32_bf16(b1hi, a2hi, d2,    0,0,0); \
    _Pragma("unroll") \
    for (int r = 0; r < 4; ++r) { \
      float e1 = fast_exp2(d1[r] * Cexp); \
      float e2 = fast_exp2(d2[r] * Cexp); \
      s1 += e1; n1 += e1 * PV[r]; \
      s2 += e2; n2 += e2 * PV[r]; \
    } }

#define STEP(BUF, P) { COMPC(BUF,0,0,P##0) COMPC(BUF,1,0,P##1) COMPC(BUF,0,32,P##2) COMPC(BUF,1,32,P##3) }

  // prologue: tile 0 in flight
  STAGEZ(0, jbeg)
  LOADPOS(PA, jbeg)
  __syncthreads();                       // vmcnt(0): tile 0 + pos(0) landed

  #pragma unroll 1
  for (int tp = 0; tp < 7; ++tp) {       // steps t = 2*tp, 2*tp+1  (0..13)
    const int t0 = tp*2;
    STAGEZ(1, jbeg + (t0+1)*64)          // issue BEFORE compute: full phase to land
    LOADPOS(PB, jbeg + (t0+1)*64)
    STEP(0, PA)
    __syncthreads();
    STAGEZ(0, jbeg + (t0+2)*64)
    LOADPOS(PA, jbeg + (t0+2)*64)
    STEP(1, PB)
    __syncthreads();
  }
  // steps 14, 15
  STAGEZ(1, jbeg + 15*64)
  LOADPOS(PB, jbeg + 15*64)
  STEP(0, PA)
  __syncthreads();
  STEP(1, PB)

#undef STAGEZ
#undef LOADPOS
#undef COMPC
#undef STEP

  // reduce j-partials across the 4 quads -> full sums per row i0+r16
  s1 += __shfl_xor(s1, 16); s1 += __shfl_xor(s1, 32);
  n1 += __shfl_xor(n1, 16); n1 += __shfl_xor(n1, 32);
  s2 += __shfl_xor(s2, 16); s2 += __shfl_xor(s2, 32);
  n2 += __shfl_xor(n2, 16); n2 += __shfl_xor(n2, 32);

  if (lane < 16) {
    int row = i0 + r16;
    atomicAdd(&rowsum1[row], s1);
    atomicAdd(&num1[row],    n1);
    atomicAdd(&rowsum2[row], s2);
    atomicAdd(&num2[row],    n2);
  }
}

// ---------------- Kernel C: final loss reduction ----------------
__global__ __launch_bounds__(1024) void loss_kernel(
    const float* __restrict__ rowsum1, const float* __restrict__ num1,
    const float* __restrict__ rowsum2, const float* __restrict__ num2,
    float* __restrict__ out)
{
  __shared__ float part[16];
  const int tid = threadIdx.x, lane = tid & 63, w = tid >> 6;
  float acc = 0.f;
  for (int i = tid; i < N; i += 1024) {
    float sc = -logf(num1[i]/(rowsum1[i]+1e-8f) + 1e-8f);
    float mp = -logf(num2[i]/(rowsum2[i]+1e-8f) + 1e-8f);
    acc += 0.5f*sc + 0.5f*mp;   // LAMBDA = 0.5
  }
  #pragma unroll
  for (int m = 1; m < 64; m <<= 1) acc += __shfl_xor(acc, m);
  if (lane == 0) part[w] = acc;
  __syncthreads();
  if (tid == 0) {
    float t = 0.f;
    #pragma unroll
    for (int k = 0; k < 16; ++k) t += part[k];
    out[0] = t * (1.0f/N);
  }
}

extern "C" void kernel_launch(void* const* d_in, const int* in_sizes, int n_in,
                              void* d_out, int out_size, void* d_ws, size_t ws_size,
                              hipStream_t stream) {
  const float* x1  = (const float*)d_in[0];
  const float* x2  = (const float*)d_in[1];
  const float* W1  = (const float*)d_in[2];
  const float* b1  = (const float*)d_in[3];
  const float* W2  = (const float*)d_in[4];
  const float* b2  = (const float*)d_in[5];
  const float* pos = (const float*)d_in[6];

  char* ws = (char*)d_ws;
  __bf16* Z1h = (__bf16*)ws;
  __bf16* Z2h = (__bf16*)(ws + (size_t)N*HID*sizeof(__bf16));
  size_t zbytes = (size_t)2*N*HID*sizeof(__bf16);   // 2 MB
  float* rowsum1 = (float*)(ws + zbytes);
  float* num1    = rowsum1 + N;
  float* rowsum2 = num1 + N;
  float* num2    = rowsum2 + N;

  proj_kernel<<<1024, 256, 0, stream>>>(x1, x2, W1, b1, W2, b2, Z1h, Z2h, rowsum1);
  sim_kernel<<<128*JC, 256, 0, stream>>>(Z1h, Z2h, pos, rowsum1, num1, rowsum2, num2);
  loss_kernel<<<1, 1024, 0, stream>>>(rowsum1, num1, rowsum2, num2, (float*)d_out);
}